// Round 13
// baseline (1379.758 us; speedup 1.0000x reference)
//
#include <hip/hip_runtime.h>
#include <math.h>

#define NBIN 49
#define NOUT 105   // 21 cls + 84 reg
#define NCLS 21
#define BM 64
#define BK 64
#define MTILES 16  // 1024 / BM

// Fused PSRoI-pool + GEMM, workspace-free.
// Round 13: bw computed as w * fl32(1/7) (reciprocal-multiply, XLA/GPU-div
// semantics). Extends the j=6 strip to w+1 for w in {3,6,9,11,12}; identical
// windows for w in {2,4,5,7,8,10,13,14} — matches the R9/R11 probe pattern.
__global__ __launch_bounds__(256) void k_pool_gemm(
    const float* __restrict__ h, const float* __restrict__ rois,
    const int* __restrict__ ridx, const float* __restrict__ Wc,
    const float* __restrict__ bc, const float* __restrict__ Wl,
    const float* __restrict__ bl, float* out) {
  const int mt  = blockIdx.x;
  const int bin = blockIdx.y;
  const int bi = bin / 7, bj = bin % 7;
  const int t = threadIdx.x;

  __shared__ float A[BM][BK + 1];
  __shared__ float Ws[NOUT + 7][BK + 1];   // 112 rows, rows >=105 zeroed
  __shared__ int   hsS[BM], heS[BM], wsS[BM], weS[BM], bS[BM];
  __shared__ float scS[BM], mkS[BM];

  if (t < BM) {
    int r = mt * BM + t;
    int x1 = (int)floorf(rois[r * 4 + 0] * 0.0625f + 0.5f);
    int y1 = (int)floorf(rois[r * 4 + 1] * 0.0625f + 0.5f);
    int x2 = (int)floorf(rois[r * 4 + 2] * 0.0625f + 0.5f);
    int y2 = (int)floorf(rois[r * 4 + 3] * 0.0625f + 0.5f);
    const float INV7 = 1.0f / 7.0f;        // fl32(1/7), correctly rounded
    float bw = (float)max(x2 - x1, 1) * INV7;   // reciprocal-multiply
    float bh = (float)max(y2 - y1, 1) * INV7;
    int ws_ = min(max((int)floorf((float)bj * bw) + x1, 0), 64);
    int we_ = min(max((int)ceilf((float)(bj + 1) * bw) + x1, 0), 64);
    int hs_ = min(max((int)floorf((float)bi * bh) + y1, 0), 64);
    int he_ = min(max((int)ceilf((float)(bi + 1) * bh) + y1, 0), 64);
    int area = (he_ - hs_) * (we_ - ws_);
    bool m = area > 0;
    scS[t] = m ? 1.0f / (49.0f * (float)area) : 0.0f;
    mkS[t] = m ? (1.0f / 49.0f) : 0.0f;
    hsS[t] = hs_;
    heS[t] = m ? he_ : hs_;   // empty loop when masked
    wsS[t] = ws_;
    weS[t] = we_;
    bS[t]  = ridx[r];
  }
  __syncthreads();

  float acc[4][7] = {};
  const int tx = t & 15, ty = t >> 4;   // tx: N-group, ty: M-group
  const int ty4 = ty * 4, tx7 = tx * 7;

  for (int c0 = 0; c0 < 1024; c0 += BK) {
    // ---- stage A: pool on the fly from NATIVE h layout [b][c][y][x] ----
#pragma unroll
    for (int rr = 0; rr < 4; ++rr) {
      int r = ty4 + rr;
      float s0 = 0.f, s1 = 0.f, s2 = 0.f, s3 = 0.f;
      const int bb = bS[r];
      const int hs = hsS[r], he = heS[r], ws = wsS[r], we = weS[r];
      const float* base = h + (size_t)(bb * 1024 + c0 + tx * 4) * 4096;
      for (int y = hs; y < he; ++y)
        for (int x = ws; x < we; ++x) {
          int sp = y * 64 + x;
          s0 += base[sp];
          s1 += base[4096 + sp];
          s2 += base[8192 + sp];
          s3 += base[12288 + sp];
        }
      float sc = scS[r];
      A[r][tx * 4 + 0] = s0 * sc;
      A[r][tx * 4 + 1] = s1 * sc;
      A[r][tx * 4 + 2] = s2 * sc;
      A[r][tx * 4 + 3] = s3 * sc;
    }
    // ---- stage W: 112 rows x 64 ch (rows >=105 zero) ----
#pragma unroll
    for (int it = 0; it < 7; ++it) {
      int idx = t + it * 256;       // 0..1791, bijective over (row, cq)
      int row = idx >> 4;
      int cq  = idx & 15;
      float4 v = {0.f, 0.f, 0.f, 0.f};
      if (row < NCLS)
        v = *(const float4*)&Wc[(size_t)(row * 49 + bin) * 1024 + c0 + cq * 4];
      else if (row < NOUT)
        v = *(const float4*)&Wl[(size_t)((row - NCLS) * 49 + bin) * 1024 + c0 + cq * 4];
      Ws[row][cq * 4 + 0] = v.x;
      Ws[row][cq * 4 + 1] = v.y;
      Ws[row][cq * 4 + 2] = v.z;
      Ws[row][cq * 4 + 3] = v.w;
    }
    __syncthreads();
    // ---- compute: 4r x 7o register tile ----
    for (int kk = 0; kk < BK; ++kk) {
      float a0 = A[ty4 + 0][kk];
      float a1 = A[ty4 + 1][kk];
      float a2 = A[ty4 + 2][kk];
      float a3 = A[ty4 + 3][kk];
#pragma unroll
      for (int oo = 0; oo < 7; ++oo) {
        float w = Ws[tx7 + oo][kk];
        acc[0][oo] += a0 * w;
        acc[1][oo] += a1 * w;
        acc[2][oo] += a2 * w;
        acc[3][oo] += a3 * w;
      }
    }
    __syncthreads();
  }

  // ---- epilogue: bias + atomic accumulate into out ----
#pragma unroll
  for (int rr = 0; rr < 4; ++rr) {
    int r = ty4 + rr;
    int gr = mt * BM + r;
#pragma unroll
    for (int oo = 0; oo < 7; ++oo) {
      int o = tx7 + oo;
      if (o < NOUT) {
        float bias = (o < NCLS) ? bc[o * 49 + bin] : bl[(o - NCLS) * 49 + bin];
        float val = acc[rr][oo] + mkS[r] * bias;
        if (o < NCLS)
          atomicAdd(&out[gr * NCLS + o], val);
        else
          atomicAdd(&out[1024 * NCLS + gr * 84 + (o - NCLS)], val);
      }
    }
  }
}

extern "C" void kernel_launch(void* const* d_in, const int* in_sizes, int n_in,
                              void* d_out, int out_size, void* d_ws, size_t ws_size,
                              hipStream_t stream) {
  const float* h    = (const float*)d_in[0];
  const float* rois = (const float*)d_in[1];
  const int*   ridx = (const int*)d_in[2];
  const float* Wc   = (const float*)d_in[3];
  const float* bc   = (const float*)d_in[4];
  const float* Wl   = (const float*)d_in[5];
  const float* bl   = (const float*)d_in[6];
  float* out = (float*)d_out;

  hipMemsetAsync(out, 0, (size_t)out_size * sizeof(float), stream);
  k_pool_gemm<<<dim3(MTILES, NBIN), 256, 0, stream>>>(h, rois, ridx, Wc, bc, Wl, bl, out);
}

// Round 14
// 572.282 us; speedup vs baseline: 2.4110x; 2.4110x over previous
//
#include <hip/hip_runtime.h>
#include <math.h>

#define NBIN 49
#define NOUT 105   // 21 cls + 84 reg
#define NCLS 21
#define BM 64
#define BK 64
#define MTILES 16  // 1024 / BM

// ---------------- K1: transpose h[b][c][y][x] -> hT[b][(y*64+x)][c] ----------------
__global__ __launch_bounds__(256) void k_transpose(const float* __restrict__ h,
                                                   float* __restrict__ hT) {
  __shared__ float tile[32][33];
  const int b  = blockIdx.z;
  const int s0 = blockIdx.x * 32;   // spatial
  const int c0 = blockIdx.y * 32;   // channel
  const int tx = threadIdx.x & 31, ty = threadIdx.x >> 5;  // ty 0..7
#pragma unroll
  for (int i = 0; i < 4; ++i) {
    int c = c0 + ty + i * 8;
    tile[ty + i * 8][tx] = h[((size_t)b * 1024 + c) * 4096 + s0 + tx];
  }
  __syncthreads();
#pragma unroll
  for (int i = 0; i < 4; ++i) {
    int s = s0 + ty + i * 8;
    hT[((size_t)b * 4096 + s) * 1024 + c0 + tx] = tile[tx][ty + i * 8];
  }
}

// ---------------- K2: in-place y-prefix-sum on hT (channels-last) ----------------
// thread owns column (b, x, c); Y[y] = sum_{y'<=y} hT[y'].
__global__ __launch_bounds__(256) void k_ycumsum(float* __restrict__ hT) {
  const int c = blockIdx.x * 256 + threadIdx.x;  // 0..1023
  const int x = blockIdx.y;                      // 0..63
  const int b = blockIdx.z;                      // 0..1
  float* p = hT + ((size_t)b * 4096 + x) * 1024 + c;
  float run = 0.f;
#pragma unroll 4
  for (int y = 0; y < 64; ++y) {
    run += p[(size_t)y * 65536];
    p[(size_t)y * 65536] = run;
  }
}

// ---------------- K3: fused PSRoI-pool (via y-prefix) + GEMM ----------------
__global__ __launch_bounds__(256) void k_pool_gemm(
    const float* __restrict__ Y, const float* __restrict__ rois,
    const int* __restrict__ ridx, const float* __restrict__ Wc,
    const float* __restrict__ bc, const float* __restrict__ Wl,
    const float* __restrict__ bl, float* out) {
  const int mt  = blockIdx.x;
  const int bin = blockIdx.y;
  const int bi = bin / 7, bj = bin % 7;
  const int t = threadIdx.x;

  __shared__ float A[BM][BK + 1];
  __shared__ float Ws[NOUT + 7][BK + 1];   // 112 rows, rows >=105 zeroed
  __shared__ int   wsS[BM], weS[BM], hiS[BM], loS[BM], bS[BM];
  __shared__ float scS[BM], mkS[BM], lsS[BM];

  if (t < BM) {
    int r = mt * BM + t;
    int x1 = (int)floorf(rois[r * 4 + 0] * 0.0625f + 0.5f);
    int y1 = (int)floorf(rois[r * 4 + 1] * 0.0625f + 0.5f);
    int x2 = (int)floorf(rois[r * 4 + 2] * 0.0625f + 0.5f);
    int y2 = (int)floorf(rois[r * 4 + 3] * 0.0625f + 0.5f);
    const float INV7 = 1.0f / 7.0f;        // fl32(1/7) — reciprocal-multiply (np-ref semantics)
    float bw = (float)max(x2 - x1, 1) * INV7;
    float bh = (float)max(y2 - y1, 1) * INV7;
    int ws_ = min(max((int)floorf((float)bj * bw) + x1, 0), 64);
    int we_ = min(max((int)ceilf((float)(bj + 1) * bw) + x1, 0), 64);
    int hs_ = min(max((int)floorf((float)bi * bh) + y1, 0), 64);
    int he_ = min(max((int)ceilf((float)(bi + 1) * bh) + y1, 0), 64);
    int area = (he_ - hs_) * (we_ - ws_);
    bool m = area > 0;
    scS[t] = m ? 1.0f / (49.0f * (float)area) : 0.0f;
    mkS[t] = m ? (1.0f / 49.0f) : 0.0f;
    wsS[t] = ws_;
    weS[t] = m ? we_ : ws_;                  // empty loop when masked
    hiS[t] = m ? (he_ - 1) * 64 : 0;         // row offset of upper prefix row
    loS[t] = max(hs_ - 1, 0) * 64;           // row offset of lower prefix row
    lsS[t] = (hs_ > 0) ? 1.0f : 0.0f;        // subtract lower row?
    bS[t]  = ridx[r];
  }
  __syncthreads();

  float acc[4][7] = {};
  const int tx = t & 15, ty = t >> 4;   // tx: N-group, ty: M-group
  const int ty4 = ty * 4, tx7 = tx * 7;

  for (int c0 = 0; c0 < 1024; c0 += BK) {
    // ---- stage A: window sum from y-prefix rows (coalesced 256B reads) ----
#pragma unroll
    for (int rr = 0; rr < 4; ++rr) {
      int r = ty4 + rr;
      float s0 = 0.f, s1 = 0.f, s2 = 0.f, s3 = 0.f;
      const int ws = wsS[r], we = weS[r], hi = hiS[r], lo = loS[r];
      const float ls = lsS[r];
      const float* baseY = Y + (size_t)bS[r] * 4096 * 1024 + c0 + tx * 4;
      for (int x = ws; x < we; ++x) {
        const float4 vh = *(const float4*)&baseY[(size_t)(hi + x) * 1024];
        const float4 vl = *(const float4*)&baseY[(size_t)(lo + x) * 1024];
        s0 += vh.x - ls * vl.x;
        s1 += vh.y - ls * vl.y;
        s2 += vh.z - ls * vl.z;
        s3 += vh.w - ls * vl.w;
      }
      float sc = scS[r];
      A[r][tx * 4 + 0] = s0 * sc;
      A[r][tx * 4 + 1] = s1 * sc;
      A[r][tx * 4 + 2] = s2 * sc;
      A[r][tx * 4 + 3] = s3 * sc;
    }
    // ---- stage W: 112 rows x 64 ch (rows >=105 zero) ----
#pragma unroll
    for (int it = 0; it < 7; ++it) {
      int idx = t + it * 256;       // 0..1791, bijective over (row, cq)
      int row = idx >> 4;
      int cq  = idx & 15;
      float4 v = {0.f, 0.f, 0.f, 0.f};
      if (row < NCLS)
        v = *(const float4*)&Wc[(size_t)(row * 49 + bin) * 1024 + c0 + cq * 4];
      else if (row < NOUT)
        v = *(const float4*)&Wl[(size_t)((row - NCLS) * 49 + bin) * 1024 + c0 + cq * 4];
      Ws[row][cq * 4 + 0] = v.x;
      Ws[row][cq * 4 + 1] = v.y;
      Ws[row][cq * 4 + 2] = v.z;
      Ws[row][cq * 4 + 3] = v.w;
    }
    __syncthreads();
    // ---- compute: 4r x 7o register tile ----
    for (int kk = 0; kk < BK; ++kk) {
      float a0 = A[ty4 + 0][kk];
      float a1 = A[ty4 + 1][kk];
      float a2 = A[ty4 + 2][kk];
      float a3 = A[ty4 + 3][kk];
#pragma unroll
      for (int oo = 0; oo < 7; ++oo) {
        float w = Ws[tx7 + oo][kk];
        acc[0][oo] += a0 * w;
        acc[1][oo] += a1 * w;
        acc[2][oo] += a2 * w;
        acc[3][oo] += a3 * w;
      }
    }
    __syncthreads();
  }

  // ---- epilogue: bias + atomic accumulate into out ----
#pragma unroll
  for (int rr = 0; rr < 4; ++rr) {
    int r = ty4 + rr;
    int gr = mt * BM + r;
#pragma unroll
    for (int oo = 0; oo < 7; ++oo) {
      int o = tx7 + oo;
      if (o < NOUT) {
        float bias = (o < NCLS) ? bc[o * 49 + bin] : bl[(o - NCLS) * 49 + bin];
        float val = acc[rr][oo] + mkS[r] * bias;
        if (o < NCLS)
          atomicAdd(&out[gr * NCLS + o], val);
        else
          atomicAdd(&out[1024 * NCLS + gr * 84 + (o - NCLS)], val);
      }
    }
  }
}

extern "C" void kernel_launch(void* const* d_in, const int* in_sizes, int n_in,
                              void* d_out, int out_size, void* d_ws, size_t ws_size,
                              hipStream_t stream) {
  const float* h    = (const float*)d_in[0];
  const float* rois = (const float*)d_in[1];
  const int*   ridx = (const int*)d_in[2];
  const float* Wc   = (const float*)d_in[3];
  const float* bc   = (const float*)d_in[4];
  const float* Wl   = (const float*)d_in[5];
  const float* bl   = (const float*)d_in[6];
  float* out = (float*)d_out;

  float* hT = (float*)d_ws;   // 2*4096*1024*4 = 33.55 MB (becomes Y in-place)

  hipMemsetAsync(out, 0, (size_t)out_size * sizeof(float), stream);
  k_transpose<<<dim3(128, 32, 2), 256, 0, stream>>>(h, hT);
  k_ycumsum<<<dim3(4, 64, 2), 256, 0, stream>>>(hT);
  k_pool_gemm<<<dim3(MTILES, NBIN), 256, 0, stream>>>(hT, rois, ridx, Wc, bc, Wl, bl, out);
}

// Round 15
// 165.580 us; speedup vs baseline: 8.3329x; 3.4562x over previous
//
#include <hip/hip_runtime.h>
#include <math.h>

#define NBIN 49
#define NOUT 105   // 21 cls + 84 reg
#define NCLS 21
#define BM 64
#define BK 64
#define MTILES 16  // 1024 / BM

typedef __attribute__((ext_vector_type(4))) float f32x4;
typedef __attribute__((ext_vector_type(8))) short bf16x8;

__device__ __forceinline__ unsigned short bf16rne(float x) {
  unsigned u = __float_as_uint(x);
  u = (u + 0x7FFFu + ((u >> 16) & 1u)) >> 16;
  return (unsigned short)u;
}

// ---------------- K1: transpose h[b][c][y][x] -> hT[b][(y*64+x)][c] ----------------
__global__ __launch_bounds__(256) void k_transpose(const float* __restrict__ h,
                                                   float* __restrict__ hT) {
  __shared__ float tile[32][33];
  const int b  = blockIdx.z;
  const int s0 = blockIdx.x * 32;   // spatial
  const int c0 = blockIdx.y * 32;   // channel
  const int tx = threadIdx.x & 31, ty = threadIdx.x >> 5;  // ty 0..7
#pragma unroll
  for (int i = 0; i < 4; ++i) {
    int c = c0 + ty + i * 8;
    tile[ty + i * 8][tx] = h[((size_t)b * 1024 + c) * 4096 + s0 + tx];
  }
  __syncthreads();
#pragma unroll
  for (int i = 0; i < 4; ++i) {
    int s = s0 + ty + i * 8;
    hT[((size_t)b * 4096 + s) * 1024 + c0 + tx] = tile[tx][ty + i * 8];
  }
}

// ---------------- K2: in-place y-prefix-sum on hT (channels-last) ----------------
__global__ __launch_bounds__(256) void k_ycumsum(float* __restrict__ hT) {
  const int c = blockIdx.x * 256 + threadIdx.x;  // 0..1023
  const int x = blockIdx.y;                      // 0..63
  const int b = blockIdx.z;                      // 0..1
  float* p = hT + ((size_t)b * 4096 + x) * 1024 + c;
  float run = 0.f;
#pragma unroll 4
  for (int y = 0; y < 64; ++y) {
    run += p[(size_t)y * 65536];
    p[(size_t)y * 65536] = run;
  }
}

// ---------------- K3: fused PSRoI-pool (via y-prefix) + bf16 MFMA GEMM ----------------
__global__ __launch_bounds__(256) void k_pool_gemm(
    const float* __restrict__ Y, const float* __restrict__ rois,
    const int* __restrict__ ridx, const float* __restrict__ Wc,
    const float* __restrict__ bc, const float* __restrict__ Wl,
    const float* __restrict__ bl, float* out) {
  const int mt  = blockIdx.x;
  const int bin = blockIdx.y;
  const int bi = bin / 7, bj = bin % 7;
  const int t = threadIdx.x;

  __shared__ unsigned short AsS[BM * BK];        // [64][64] bf16, XOR-swizzled
  __shared__ unsigned short WlS[(NOUT + 7) * BK];// [112][64] bf16, XOR-swizzled
  __shared__ int   wsS[BM], weS[BM], hiS[BM], loS[BM], bS[BM];
  __shared__ float scS[BM], mkS[BM], lsS[BM];

  if (t < BM) {
    int r = mt * BM + t;
    int x1 = (int)floorf(rois[r * 4 + 0] * 0.0625f + 0.5f);
    int y1 = (int)floorf(rois[r * 4 + 1] * 0.0625f + 0.5f);
    int x2 = (int)floorf(rois[r * 4 + 2] * 0.0625f + 0.5f);
    int y2 = (int)floorf(rois[r * 4 + 3] * 0.0625f + 0.5f);
    const float INV7 = 1.0f / 7.0f;        // reciprocal-multiply (np-ref semantics)
    float bw = (float)max(x2 - x1, 1) * INV7;
    float bh = (float)max(y2 - y1, 1) * INV7;
    int ws_ = min(max((int)floorf((float)bj * bw) + x1, 0), 64);
    int we_ = min(max((int)ceilf((float)(bj + 1) * bw) + x1, 0), 64);
    int hs_ = min(max((int)floorf((float)bi * bh) + y1, 0), 64);
    int he_ = min(max((int)ceilf((float)(bi + 1) * bh) + y1, 0), 64);
    int area = (he_ - hs_) * (we_ - ws_);
    bool m = area > 0;
    scS[t] = m ? 1.0f / (49.0f * (float)area) : 0.0f;
    mkS[t] = m ? (1.0f / 49.0f) : 0.0f;
    wsS[t] = ws_;
    weS[t] = m ? we_ : ws_;                  // empty loop when masked
    hiS[t] = m ? (he_ - 1) * 64 : 0;
    loS[t] = max(hs_ - 1, 0) * 64;
    lsS[t] = (hs_ > 0) ? 1.0f : 0.0f;
    bS[t]  = ridx[r];
  }
  __syncthreads();

  const int tx = t & 15, ty = t >> 4;   // staging decomposition
  const int ty4 = ty * 4;
  const int w = t >> 6;                 // wave id 0..3 (m-tile)
  const int l = t & 63;
  const int lrow = l & 15, lk8 = (l >> 4) * 8;

  f32x4 acc[7];
#pragma unroll
  for (int nt = 0; nt < 7; ++nt) acc[nt] = (f32x4){0.f, 0.f, 0.f, 0.f};

  for (int c0 = 0; c0 < 1024; c0 += BK) {
    // ---- stage A: window sum from y-prefix rows -> bf16 LDS (swizzled) ----
#pragma unroll
    for (int rr = 0; rr < 4; ++rr) {
      int r = ty4 + rr;
      float s0 = 0.f, s1 = 0.f, s2 = 0.f, s3 = 0.f;
      const int ws = wsS[r], we = weS[r], hi = hiS[r], lo = loS[r];
      const float ls = lsS[r];
      const float* baseY = Y + (size_t)bS[r] * 4096 * 1024 + c0 + tx * 4;
      for (int x = ws; x < we; ++x) {
        const float4 vh = *(const float4*)&baseY[(size_t)(hi + x) * 1024];
        const float4 vl = *(const float4*)&baseY[(size_t)(lo + x) * 1024];
        s0 += vh.x - ls * vl.x;
        s1 += vh.y - ls * vl.y;
        s2 += vh.z - ls * vl.z;
        s3 += vh.w - ls * vl.w;
      }
      float sc = scS[r];
      unsigned p0 = (unsigned)bf16rne(s0 * sc) | ((unsigned)bf16rne(s1 * sc) << 16);
      unsigned p1 = (unsigned)bf16rne(s2 * sc) | ((unsigned)bf16rne(s3 * sc) << 16);
      int idx = (r * BK + tx * 4) ^ ((r & 7) << 3);
      *(uint2*)&AsS[idx] = make_uint2(p0, p1);
    }
    // ---- stage W: 112 rows x 64 ch -> bf16 LDS (swizzled; rows >=105 zero) ----
#pragma unroll
    for (int it = 0; it < 7; ++it) {
      int idx = t + it * 256;       // 0..1791, bijective over (row, cq)
      int row = idx >> 4;
      int cq  = idx & 15;
      float4 v = {0.f, 0.f, 0.f, 0.f};
      if (row < NCLS)
        v = *(const float4*)&Wc[(size_t)(row * 49 + bin) * 1024 + c0 + cq * 4];
      else if (row < NOUT)
        v = *(const float4*)&Wl[(size_t)((row - NCLS) * 49 + bin) * 1024 + c0 + cq * 4];
      unsigned p0 = (unsigned)bf16rne(v.x) | ((unsigned)bf16rne(v.y) << 16);
      unsigned p1 = (unsigned)bf16rne(v.z) | ((unsigned)bf16rne(v.w) << 16);
      int widx = (row * BK + cq * 4) ^ ((row & 7) << 3);
      *(uint2*)&WlS[widx] = make_uint2(p0, p1);
    }
    __syncthreads();

    // ---- MFMA: wave w owns m-tile w (16 RoIs) x 7 n-tiles, K=64 ----
    bf16x8 af[2];
#pragma unroll
    for (int ks = 0; ks < 2; ++ks) {
      int r = w * 16 + lrow;
      int k = ks * 32 + lk8;
      int ai = (r * BK + k) ^ ((r & 7) << 3);
      af[ks] = *(const bf16x8*)&AsS[ai];
    }
#pragma unroll
    for (int nt = 0; nt < 7; ++nt) {
#pragma unroll
      for (int ks = 0; ks < 2; ++ks) {
        int row = nt * 16 + lrow;
        int k = ks * 32 + lk8;
        int bix = (row * BK + k) ^ ((row & 7) << 3);
        bf16x8 bf = *(const bf16x8*)&WlS[bix];
        acc[nt] = __builtin_amdgcn_mfma_f32_16x16x32_bf16(af[ks], bf, acc[nt], 0, 0, 0);
      }
    }
    __syncthreads();
  }

  // ---- epilogue: bias + atomic accumulate. D layout: n=l&15, m=4*(l>>4)+b ----
#pragma unroll
  for (int nt = 0; nt < 7; ++nt) {
    int o = nt * 16 + (l & 15);
    if (o < NOUT) {
      float bias = (o < NCLS) ? bc[o * 49 + bin] : bl[(o - NCLS) * 49 + bin];
#pragma unroll
      for (int b = 0; b < 4; ++b) {
        int r_loc = w * 16 + 4 * (l >> 4) + b;
        int gr = mt * BM + r_loc;
        float val = acc[nt][b] + mkS[r_loc] * bias;
        if (o < NCLS)
          atomicAdd(&out[gr * NCLS + o], val);
        else
          atomicAdd(&out[1024 * NCLS + gr * 84 + (o - NCLS)], val);
      }
    }
  }
}

extern "C" void kernel_launch(void* const* d_in, const int* in_sizes, int n_in,
                              void* d_out, int out_size, void* d_ws, size_t ws_size,
                              hipStream_t stream) {
  const float* h    = (const float*)d_in[0];
  const float* rois = (const float*)d_in[1];
  const int*   ridx = (const int*)d_in[2];
  const float* Wc   = (const float*)d_in[3];
  const float* bc   = (const float*)d_in[4];
  const float* Wl   = (const float*)d_in[5];
  const float* bl   = (const float*)d_in[6];
  float* out = (float*)d_out;

  float* hT = (float*)d_ws;   // 33.55 MB (becomes y-prefix Y in-place)

  hipMemsetAsync(out, 0, (size_t)out_size * sizeof(float), stream);
  k_transpose<<<dim3(128, 32, 2), 256, 0, stream>>>(h, hT);
  k_ycumsum<<<dim3(4, 64, 2), 256, 0, stream>>>(hT);
  k_pool_gemm<<<dim3(MTILES, NBIN), 256, 0, stream>>>(hT, rois, ridx, Wc, bc, Wl, bl, out);
}